// Round 10
// baseline (488.368 us; speedup 1.0000x reference)
//
#include <hip/hip_runtime.h>

// ---------------------------------------------------------------------------
// CustomGCN: 2 dense layers + 3 GCNConv layers + per-layer (max||mean) pool.
// R1: binary-search cntG.  R2: bf16 pipeline + MFMA GEMMs + bf16 gather.
// R3: 8-deep agg gather pipeline.  R4: one u64 atomic/edge CSC build.
// R5: interleaved CSC record.  R6: 4B rec ((bf16w)<<17|src), u8 eslot.
// R7: agg back to 8-deep.  R8: block-range fusion (p1||gemm1, scan||gemm, pool||gemm).
// R9: k_agg 2 waves/node with interleaved 8-edge chunks + LDS combine —
//     halves the per-node dependent-latency chain (agg was latency-exposed
//     at 35% HBM, not BW-bound).
// ---------------------------------------------------------------------------

typedef __attribute__((ext_vector_type(8))) short bf16x8;
typedef __attribute__((ext_vector_type(4))) float f32x4;
typedef unsigned long long u64;
typedef unsigned int u32;

#define FRACBITS 52
#define FRACMASK ((1ULL << FRACBITS) - 1ULL)

__device__ __forceinline__ unsigned short f2b(float f) {  // RNE f32->bf16
    unsigned int u = __float_as_uint(f);
    return (unsigned short)((u + 0x7fffu + ((u >> 16) & 1u)) >> 16);
}
__device__ __forceinline__ float b2f(unsigned short h) {
    return __uint_as_float((unsigned int)h << 16);
}

// ---------------- device bodies --------------------------------------------

__device__ __forceinline__ void gemm_dev(int bidx, int t,
                                         const unsigned short* __restrict__ A,
                                         const float* __restrict__ Af32,
                                         const unsigned short* __restrict__ Wf,
                                         const float* __restrict__ bias,
                                         unsigned short* __restrict__ C,
                                         int relu, int M)
{
    int lane = t & 63, w = t >> 6;
    int s = bidx * 4 + w;
    if (s * 16 >= M) return;
    int r0 = s * 16;
    int row = r0 + (lane & 15);
    int k0 = (lane >> 4) * 8;

    bf16x8 af[4];
    if (A) {
#pragma unroll
        for (int kt = 0; kt < 4; ++kt) {
            bf16x8 a = {0,0,0,0,0,0,0,0};
            if (row < M) a = *(const bf16x8*)&A[(size_t)row * 128 + k0 + kt * 32];
            af[kt] = a;
        }
    } else {
#pragma unroll
        for (int kt = 0; kt < 4; ++kt) {
            bf16x8 a = {0,0,0,0,0,0,0,0};
            if (row < M) {
                const float4* A4 = (const float4*)(Af32 + (size_t)row * 128 + k0 + kt * 32);
                float4 p = A4[0], q = A4[1];
                a[0] = (short)f2b(p.x); a[1] = (short)f2b(p.y);
                a[2] = (short)f2b(p.z); a[3] = (short)f2b(p.w);
                a[4] = (short)f2b(q.x); a[5] = (short)f2b(q.y);
                a[6] = (short)f2b(q.z); a[7] = (short)f2b(q.w);
            }
            af[kt] = a;
        }
    }

    int orow = r0 + 4 * (lane >> 4);
    int ocol = lane & 15;
#pragma unroll
    for (int ct = 0; ct < 8; ++ct) {
        f32x4 acc = {0.f, 0.f, 0.f, 0.f};
#pragma unroll
        for (int kt = 0; kt < 4; ++kt) {
            bf16x8 b = *(const bf16x8*)&Wf[(size_t)(((ct << 2) | kt) * 64 + lane) * 8];
            acc = __builtin_amdgcn_mfma_f32_16x16x32_bf16(af[kt], b, acc, 0, 0, 0);
        }
        float bv = bias ? bias[ct * 16 + ocol] : 0.f;
#pragma unroll
        for (int j = 0; j < 4; ++j) {
            int rr = orow + j;
            if (rr < M) {
                float v = acc[j] + bv;
                if (relu) v = fmaxf(v, 0.f);
                C[(size_t)rr * 128 + ct * 16 + ocol] = f2b(v);
            }
        }
    }
}

__device__ __forceinline__ void pool_dev(int bidx, int t,
                                         const unsigned short* __restrict__ h,
                                         const int* __restrict__ batch,
                                         float* gmax, float* gsum, int n)
{
    int c = t & 127, sub = t >> 7;
    int r0 = bidx * 128;
    int rend = min(r0 + 128, n);
    float mx = 0.f, sm = 0.f;
    int cur = -1;
    for (int r = r0 + sub; r < rend; r += 2) {
        int b = batch[r];
        if (b != cur) {
            if (cur >= 0) {
                atomicMax((unsigned int*)&gmax[cur * 128 + c], __float_as_uint(mx));
                atomicAdd(&gsum[cur * 128 + c], sm);
            }
            cur = b; mx = 0.f; sm = 0.f;
        }
        float v = b2f(h[(size_t)r * 128 + c]);
        mx = fmaxf(mx, v);
        sm += v;
    }
    if (cur >= 0) {
        atomicMax((unsigned int*)&gmax[cur * 128 + c], __float_as_uint(mx));
        atomicAdd(&gsum[cur * 128 + c], sm);
    }
}

// ---------------- fused kernels --------------------------------------------

__global__ __launch_bounds__(256) void k_setup(u64* __restrict__ pk,
                                               float* __restrict__ gmax, float* __restrict__ gsum,
                                               int n, int npool,
                                               const float* __restrict__ W1, const float* __restrict__ W2,
                                               const float* __restrict__ cW,
                                               unsigned short* __restrict__ wfall,
                                               int nInit, int nWf,
                                               const int* __restrict__ batch, float* __restrict__ cntG, int g)
{
    int b = blockIdx.x;
    if (b < nInit) {
        int i = b * 256 + threadIdx.x;
        if (i < n) pk[i] = 0ULL;
        if (i < npool) { gmax[i] = 0.0f; gsum[i] = 0.0f; }
    } else if (b < nInit + nWf) {
        int wb = b - nInit;
        int m = wb >> 3;
        const float* W = (m == 0) ? W1 : (m == 1) ? W2 : (cW + (size_t)(m - 2) * 16384);
        unsigned short* Wf = wfall + (size_t)m * 16384;
        int idx = (wb & 7) * 256 + threadIdx.x;   // [0, 2048)
        int ctkt = idx >> 6, lane = idx & 63;
        int kt = ctkt & 3, ct = ctkt >> 2;
        int k0 = kt * 32 + (lane >> 4) * 8;
        int col = ct * 16 + (lane & 15);
        bf16x8 v;
#pragma unroll
        for (int j = 0; j < 8; ++j) v[j] = (short)f2b(W[(k0 + j) * 128 + col]);
        *(bf16x8*)&Wf[(size_t)idx * 8] = v;
    } else {
        int t = threadIdx.x;
        if (t < g) {
            int lo0 = 0, hi0 = n;
            while (lo0 < hi0) { int m = (lo0 + hi0) >> 1; if (batch[m] < t) lo0 = m + 1; else hi0 = m; }
            int lo1 = lo0, hi1 = n, t1 = t + 1;
            while (lo1 < hi1) { int m = (lo1 + hi1) >> 1; if (batch[m] < t1) lo1 = m + 1; else hi1 = m; }
            cntG[t] = (float)(lo1 - lo0);
        }
    }
}

__global__ __launch_bounds__(256) void k_p1_gemm(const int* __restrict__ ei, const float* __restrict__ ew,
                                                 u64* pk, unsigned char* __restrict__ eslot, int e, int p1b,
                                                 const float* __restrict__ Af32,
                                                 const unsigned short* __restrict__ Wf,
                                                 const float* __restrict__ bias,
                                                 unsigned short* __restrict__ C, int M)
{
    if (blockIdx.x < p1b) {
        int i = blockIdx.x * 256 + threadIdx.x;
        if (i >= e) return;
        int c = ei[e + i];
        float w = ew[i];
        u64 fixed = (u64)((double)w * 4294967296.0);
        u64 packed = (1ULL << FRACBITS) | fixed;
        u64 old = atomicAdd(&pk[c], packed);
        eslot[i] = (unsigned char)(old >> FRACBITS);
    } else {
        gemm_dev(blockIdx.x - p1b, threadIdx.x, nullptr, Af32, Wf, bias, C, 1, M);
    }
}

__global__ __launch_bounds__(256) void k_scan1_gemm(const u64* __restrict__ pk,
                                                    int* __restrict__ start, float* __restrict__ dinv,
                                                    int* __restrict__ partials, int n, int s1b,
                                                    const unsigned short* __restrict__ A,
                                                    const unsigned short* __restrict__ Wf,
                                                    const float* __restrict__ bias,
                                                    unsigned short* __restrict__ C, int M)
{
    __shared__ int s[256];
    if (blockIdx.x < s1b) {
        int t = threadIdx.x;
        int base = blockIdx.x * 1024 + t * 4;
        int v[4];
#pragma unroll
        for (int j = 0; j < 4; ++j) {
            int idx = base + j;
            if (idx < n) {
                u64 q = pk[idx];
                v[j] = (int)(q >> FRACBITS);
                float deg = 1.0f + (float)((double)(q & FRACMASK) * (1.0 / 4294967296.0));
                dinv[idx] = 1.0f / sqrtf(deg);
            } else v[j] = 0;
        }
        int tsum = v[0] + v[1] + v[2] + v[3];
        s[t] = tsum; __syncthreads();
        for (int off = 1; off < 256; off <<= 1) {
            int xv = (t >= off) ? s[t - off] : 0;
            __syncthreads();
            s[t] += xv;
            __syncthreads();
        }
        if (t == 255) partials[blockIdx.x] = s[255];
        int run = s[t] - tsum;
#pragma unroll
        for (int j = 0; j < 4; ++j) { int idx = base + j; if (idx < n) start[idx] = run; run += v[j]; }
    } else {
        gemm_dev(blockIdx.x - s1b, threadIdx.x, A, nullptr, Wf, bias, C, 1, M);
    }
}

__global__ __launch_bounds__(256) void k_scan2_gemm(int* partials, int nb,
                                                    const unsigned short* __restrict__ A,
                                                    const unsigned short* __restrict__ Wf,
                                                    unsigned short* __restrict__ C, int M)
{
    __shared__ int s[256];
    if (blockIdx.x == 0) {
        int t = threadIdx.x;
        int offset = 0;
        for (int b0 = 0; b0 < nb; b0 += 256) {
            int v = (b0 + t < nb) ? partials[b0 + t] : 0;
            s[t] = v; __syncthreads();
            for (int off = 1; off < 256; off <<= 1) {
                int xv = (t >= off) ? s[t - off] : 0;
                __syncthreads();
                s[t] += xv;
                __syncthreads();
            }
            int excl = s[t] - v;
            int tot = s[255];
            if (b0 + t < nb) partials[b0 + t] = offset + excl;
            offset += tot;
            __syncthreads();
        }
    } else {
        gemm_dev(blockIdx.x - 1, threadIdx.x, A, nullptr, Wf, nullptr, C, 0, M);
    }
}

__global__ __launch_bounds__(256) void k_scan3(int* __restrict__ start,
                                               const int* __restrict__ partials, int n, int total)
{
    int i = blockIdx.x * 256 + threadIdx.x;
    if (i < n) start[i] += partials[i >> 10];
    if (i == 0) start[n] = total;
}

__global__ __launch_bounds__(256) void k_phase2(const int* __restrict__ ei, const float* __restrict__ ew,
                                                const float* __restrict__ dinv,
                                                const int* __restrict__ start,
                                                const unsigned char* __restrict__ eslot,
                                                u32* __restrict__ rec, int e)
{
    int i = blockIdx.x * 256 + threadIdx.x;
    if (i >= e) return;
    int r = ei[i], c = ei[e + i];
    int idx = start[c] + eslot[i];
    float w = dinv[r] * ew[i] * dinv[c];           // w >= 0
    u32 wb = f2b(w);
    rec[idx] = (wb << 17) | (u32)r;                 // requires N < 2^17
}

// ---- pull aggregation: 2 waves/node, interleaved 8-edge chunks, LDS merge --
__global__ __launch_bounds__(256) void k_agg(const u32* __restrict__ xw,
                                             const int* __restrict__ start,
                                             const u32* __restrict__ rec,
                                             const float* __restrict__ dinv, const float* __restrict__ bias,
                                             u32* __restrict__ hout, int n)
{
    __shared__ float partsm[2][64][2];
    int t = threadIdx.x;
    int waveid = t >> 6;          // 0..3
    int lane = t & 63;
    int sub = waveid >> 1;        // node slot in block
    int w = waveid & 1;           // wave within node
    int wid = blockIdx.x * 2 + sub;
    bool active = wid < n;

    float ax = 0.f, ay = 0.f;
    if (active) {
        int s0 = start[wid], s1 = start[wid + 1];
        if (w == 0) {
            float di = dinv[wid];
            float sn = di * di;
            u32 v = xw[(size_t)wid * 64 + lane];
            ax = __uint_as_float(v << 16) * sn;
            ay = __uint_as_float(v & 0xffff0000u) * sn;
        }
        int j = s0 + w * 8;
        for (; j + 8 <= s1; j += 16) {
            u32 rc[8];
#pragma unroll
            for (int q = 0; q < 8; ++q) rc[q] = rec[j + q];
            u32 u[8];
#pragma unroll
            for (int q = 0; q < 8; ++q) u[q] = xw[(size_t)(rc[q] & 0x1FFFFu) * 64 + lane];
#pragma unroll
            for (int q = 0; q < 8; ++q) {
                float wv = __uint_as_float((rc[q] >> 17) << 16);
                ax = fmaf(wv, __uint_as_float(u[q] << 16), ax);
                ay = fmaf(wv, __uint_as_float(u[q] & 0xffff0000u), ay);
            }
        }
        int rem = s1 - j;
        if (rem > 0) {                        // rem < 8 by construction
            u32 rc[8];
#pragma unroll
            for (int q = 0; q < 8; ++q) rc[q] = (q < rem) ? rec[j + q] : 0u;
            u32 u[8];
#pragma unroll
            for (int q = 0; q < 8; ++q) u[q] = (q < rem) ? xw[(size_t)(rc[q] & 0x1FFFFu) * 64 + lane] : 0u;
#pragma unroll
            for (int q = 0; q < 8; ++q) {
                float wv = __uint_as_float((rc[q] >> 17) << 16);
                ax = fmaf(wv, __uint_as_float(u[q] << 16), ax);
                ay = fmaf(wv, __uint_as_float(u[q] & 0xffff0000u), ay);
            }
        }
        if (w == 1) { partsm[sub][lane][0] = ax; partsm[sub][lane][1] = ay; }
    }
    __syncthreads();
    if (active && w == 0) {
        ax += partsm[sub][lane][0];
        ay += partsm[sub][lane][1];
        ax = fmaxf(ax + bias[lane * 2], 0.f);
        ay = fmaxf(ay + bias[lane * 2 + 1], 0.f);
        hout[(size_t)wid * 64 + lane] = (u32)f2b(ax) | ((u32)f2b(ay) << 16);
    }
}

__global__ __launch_bounds__(256) void k_pool_gemm(const unsigned short* __restrict__ h,
                                                   const int* __restrict__ batch,
                                                   float* gmax, float* gsum, int n, int pb,
                                                   const unsigned short* __restrict__ Wf,
                                                   unsigned short* __restrict__ C, int M)
{
    if (blockIdx.x < pb) {
        pool_dev(blockIdx.x, threadIdx.x, h, batch, gmax, gsum, n);
    } else {
        gemm_dev(blockIdx.x - pb, threadIdx.x, h, nullptr, Wf, nullptr, C, 0, M);
    }
}

__global__ __launch_bounds__(256) void k_pool(const unsigned short* __restrict__ h,
                                              const int* __restrict__ batch,
                                              float* gmax, float* gsum, int n)
{
    pool_dev(blockIdx.x, threadIdx.x, h, batch, gmax, gsum, n);
}

__global__ __launch_bounds__(256) void k_final(const float* __restrict__ gmax, const float* __restrict__ gsum,
                                               const float* __restrict__ cntG, float* __restrict__ out,
                                               int G, int L)
{
    int i = blockIdx.x * 256 + threadIdx.x;
    int tot = L * G * 128;
    if (i >= tot) return;
    int c = i & 127;
    int g = (i >> 7) % G;
    int l = i / (G * 128);
    float ct = fmaxf(cntG[g], 1.0f);
    out[(size_t)g * (L * 256) + l * 256 + c]       = gmax[i];
    out[(size_t)g * (L * 256) + l * 256 + 128 + c] = gsum[i] / ct;
}

static inline int divup(int a, int b) { return (a + b - 1) / b; }

extern "C" void kernel_launch(void* const* d_in, const int* in_sizes, int n_in,
                              void* d_out, int out_size, void* d_ws, size_t ws_size,
                              hipStream_t stream)
{
    const float* x     = (const float*)d_in[0];
    const float* ew    = (const float*)d_in[1];
    const float* W1    = (const float*)d_in[2];
    const float* b1    = (const float*)d_in[3];
    const float* W2    = (const float*)d_in[4];
    const float* b2    = (const float*)d_in[5];
    const float* cW    = (const float*)d_in[6];
    const float* cB    = (const float*)d_in[7];
    const int*   ei    = (const int*)d_in[8];
    const int*   batch = (const int*)d_in[9];
    float* out = (float*)d_out;

    const int E = in_sizes[1];
    const int N = in_sizes[9];
    const int L = in_sizes[7] / 128;
    const int G = out_size / (L * 256);

    char* p = (char*)d_ws;
    auto carve = [&](size_t bytes) -> void* {
        void* q = (void*)p;
        p += (bytes + 255) & ~(size_t)255;
        return q;
    };
    u64*   pk       = (u64*)  carve((size_t)N * 8);
    float* dinv     = (float*)carve((size_t)N * 4);
    int*   start    = (int*)  carve((size_t)(N + 1) * 4);
    unsigned char* eslot = (unsigned char*)carve((size_t)E);
    int*   partials = (int*)  carve(4096);
    u32*   rec      = (u32*)  carve((size_t)E * 4);
    float* gmax     = (float*)carve((size_t)L * G * 128 * 4);
    float* gsum     = (float*)carve((size_t)L * G * 128 * 4);
    float* cntG     = (float*)carve((size_t)G * 4);
    unsigned short* wfall = (unsigned short*)carve((size_t)(2 + 3) * 16384 * 2);
    unsigned short* xwb = (unsigned short*)carve((size_t)N * 128 * 2);
    unsigned short* hbA = (unsigned short*)carve((size_t)N * 128 * 2);
    unsigned short* hbB = (unsigned short*)carve((size_t)N * 128 * 2);

    const int npool = L * G * 128;
    const int nconv = (L < 3 ? L : 3);

    // --- setup: init || wfrag x(2+nconv) || gcnt ---------------------------
    int nInit = divup(N > npool ? N : npool, 256);
    int nWf = (2 + nconv) * 8;
    k_setup<<<nInit + nWf + 1, 256, 0, stream>>>(pk, gmax, gsum, N, npool,
                                                 W1, W2, cW, wfall, nInit, nWf,
                                                 batch, cntG, G);

    int p1b = divup(E, 256);
    int gblocks = divup(N, 64);
    int pblocks = divup(N, 128);
    int ablocks = divup(N, 2);

    // --- phase1 || GEMM1 ---------------------------------------------------
    k_p1_gemm<<<p1b + gblocks, 256, 0, stream>>>(ei, ew, pk, eslot, E, p1b,
                                                 x, wfall, b1, hbA, N);

    // --- scan1 || GEMM2 ----------------------------------------------------
    int nb1 = divup(N, 1024);
    k_scan1_gemm<<<nb1 + gblocks, 256, 0, stream>>>(pk, start, dinv, partials, N, nb1,
                                                    hbA, wfall + 16384, b2, hbB, N);

    // --- scan2 || conv GEMM l0 --------------------------------------------
    k_scan2_gemm<<<1 + gblocks, 256, 0, stream>>>(partials, nb1,
                                                  hbB, wfall + 2 * 16384, xwb, N);

    k_scan3<<<divup(N, 256), 256, 0, stream>>>(start, partials, N, E);
    k_phase2<<<divup(E, 256), 256, 0, stream>>>(ei, ew, dinv, start, eslot, rec, E);

    // --- conv layers: agg -> (pool || next conv GEMM) ----------------------
    unsigned short* cur = hbB;
    unsigned short* alt = hbA;
    for (int l = 0; l < L; ++l) {
        k_agg<<<ablocks, 256, 0, stream>>>((const u32*)xwb, start, rec, dinv,
                                           cB + (size_t)l * 128, (u32*)alt, N);
        if (l + 1 < L) {
            int wi = 2 + (l + 1 < nconv ? l + 1 : nconv - 1);
            k_pool_gemm<<<pblocks + gblocks, 256, 0, stream>>>(alt, batch,
                                                               gmax + (size_t)l * G * 128,
                                                               gsum + (size_t)l * G * 128, N, pblocks,
                                                               wfall + (size_t)wi * 16384, xwb, N);
        } else {
            k_pool<<<pblocks, 256, 0, stream>>>(alt, batch,
                                                gmax + (size_t)l * G * 128,
                                                gsum + (size_t)l * G * 128, N);
        }
        unsigned short* tmp = cur; cur = alt; alt = tmp;
    }

    k_final<<<divup(L * G * 128, 256), 256, 0, stream>>>(gmax, gsum, cntG, out, G, L);
}

// Round 11
// 480.387 us; speedup vs baseline: 1.0166x; 1.0166x over previous
//
#include <hip/hip_runtime.h>

// ---------------------------------------------------------------------------
// CustomGCN: 2 dense layers + 3 GCNConv layers + per-layer (max||mean) pool.
// R1: binary-search cntG.  R2: bf16 pipeline + MFMA GEMMs + bf16 gather.
// R3: 8-deep agg gather pipeline.  R4: one u64 atomic/edge CSC build.
// R5: interleaved CSC record.  R6: 4B rec ((bf16w)<<17|src), u8 eslot.
// R7: agg 8-deep 1-wave (16-deep regressed).  R8: block-range fusion.
// R9: 2-wave agg REGRESSED (agg is fabric-throughput-bound, not latency).
// R10: agg reverted to R7 form; scan3 fused into phase2 (separate startF
//      array avoids the read/write race; phase2 recomputes its own base).
// ---------------------------------------------------------------------------

typedef __attribute__((ext_vector_type(8))) short bf16x8;
typedef __attribute__((ext_vector_type(4))) float f32x4;
typedef unsigned long long u64;
typedef unsigned int u32;

#define FRACBITS 52
#define FRACMASK ((1ULL << FRACBITS) - 1ULL)

__device__ __forceinline__ unsigned short f2b(float f) {  // RNE f32->bf16
    unsigned int u = __float_as_uint(f);
    return (unsigned short)((u + 0x7fffu + ((u >> 16) & 1u)) >> 16);
}
__device__ __forceinline__ float b2f(unsigned short h) {
    return __uint_as_float((unsigned int)h << 16);
}

// ---------------- device bodies --------------------------------------------

__device__ __forceinline__ void gemm_dev(int bidx, int t,
                                         const unsigned short* __restrict__ A,
                                         const float* __restrict__ Af32,
                                         const unsigned short* __restrict__ Wf,
                                         const float* __restrict__ bias,
                                         unsigned short* __restrict__ C,
                                         int relu, int M)
{
    int lane = t & 63, w = t >> 6;
    int s = bidx * 4 + w;
    if (s * 16 >= M) return;
    int r0 = s * 16;
    int row = r0 + (lane & 15);
    int k0 = (lane >> 4) * 8;

    bf16x8 af[4];
    if (A) {
#pragma unroll
        for (int kt = 0; kt < 4; ++kt) {
            bf16x8 a = {0,0,0,0,0,0,0,0};
            if (row < M) a = *(const bf16x8*)&A[(size_t)row * 128 + k0 + kt * 32];
            af[kt] = a;
        }
    } else {
#pragma unroll
        for (int kt = 0; kt < 4; ++kt) {
            bf16x8 a = {0,0,0,0,0,0,0,0};
            if (row < M) {
                const float4* A4 = (const float4*)(Af32 + (size_t)row * 128 + k0 + kt * 32);
                float4 p = A4[0], q = A4[1];
                a[0] = (short)f2b(p.x); a[1] = (short)f2b(p.y);
                a[2] = (short)f2b(p.z); a[3] = (short)f2b(p.w);
                a[4] = (short)f2b(q.x); a[5] = (short)f2b(q.y);
                a[6] = (short)f2b(q.z); a[7] = (short)f2b(q.w);
            }
            af[kt] = a;
        }
    }

    int orow = r0 + 4 * (lane >> 4);
    int ocol = lane & 15;
#pragma unroll
    for (int ct = 0; ct < 8; ++ct) {
        f32x4 acc = {0.f, 0.f, 0.f, 0.f};
#pragma unroll
        for (int kt = 0; kt < 4; ++kt) {
            bf16x8 b = *(const bf16x8*)&Wf[(size_t)(((ct << 2) | kt) * 64 + lane) * 8];
            acc = __builtin_amdgcn_mfma_f32_16x16x32_bf16(af[kt], b, acc, 0, 0, 0);
        }
        float bv = bias ? bias[ct * 16 + ocol] : 0.f;
#pragma unroll
        for (int j = 0; j < 4; ++j) {
            int rr = orow + j;
            if (rr < M) {
                float v = acc[j] + bv;
                if (relu) v = fmaxf(v, 0.f);
                C[(size_t)rr * 128 + ct * 16 + ocol] = f2b(v);
            }
        }
    }
}

__device__ __forceinline__ void pool_dev(int bidx, int t,
                                         const unsigned short* __restrict__ h,
                                         const int* __restrict__ batch,
                                         float* gmax, float* gsum, int n)
{
    int c = t & 127, sub = t >> 7;
    int r0 = bidx * 128;
    int rend = min(r0 + 128, n);
    float mx = 0.f, sm = 0.f;
    int cur = -1;
    for (int r = r0 + sub; r < rend; r += 2) {
        int b = batch[r];
        if (b != cur) {
            if (cur >= 0) {
                atomicMax((unsigned int*)&gmax[cur * 128 + c], __float_as_uint(mx));
                atomicAdd(&gsum[cur * 128 + c], sm);
            }
            cur = b; mx = 0.f; sm = 0.f;
        }
        float v = b2f(h[(size_t)r * 128 + c]);
        mx = fmaxf(mx, v);
        sm += v;
    }
    if (cur >= 0) {
        atomicMax((unsigned int*)&gmax[cur * 128 + c], __float_as_uint(mx));
        atomicAdd(&gsum[cur * 128 + c], sm);
    }
}

// ---------------- fused kernels --------------------------------------------

__global__ __launch_bounds__(256) void k_setup(u64* __restrict__ pk,
                                               float* __restrict__ gmax, float* __restrict__ gsum,
                                               int n, int npool,
                                               const float* __restrict__ W1, const float* __restrict__ W2,
                                               const float* __restrict__ cW,
                                               unsigned short* __restrict__ wfall,
                                               int nInit, int nWf,
                                               const int* __restrict__ batch, float* __restrict__ cntG, int g)
{
    int b = blockIdx.x;
    if (b < nInit) {
        int i = b * 256 + threadIdx.x;
        if (i < n) pk[i] = 0ULL;
        if (i < npool) { gmax[i] = 0.0f; gsum[i] = 0.0f; }
    } else if (b < nInit + nWf) {
        int wb = b - nInit;
        int m = wb >> 3;
        const float* W = (m == 0) ? W1 : (m == 1) ? W2 : (cW + (size_t)(m - 2) * 16384);
        unsigned short* Wf = wfall + (size_t)m * 16384;
        int idx = (wb & 7) * 256 + threadIdx.x;   // [0, 2048)
        int ctkt = idx >> 6, lane = idx & 63;
        int kt = ctkt & 3, ct = ctkt >> 2;
        int k0 = kt * 32 + (lane >> 4) * 8;
        int col = ct * 16 + (lane & 15);
        bf16x8 v;
#pragma unroll
        for (int j = 0; j < 8; ++j) v[j] = (short)f2b(W[(k0 + j) * 128 + col]);
        *(bf16x8*)&Wf[(size_t)idx * 8] = v;
    } else {
        int t = threadIdx.x;
        if (t < g) {
            int lo0 = 0, hi0 = n;
            while (lo0 < hi0) { int m = (lo0 + hi0) >> 1; if (batch[m] < t) lo0 = m + 1; else hi0 = m; }
            int lo1 = lo0, hi1 = n, t1 = t + 1;
            while (lo1 < hi1) { int m = (lo1 + hi1) >> 1; if (batch[m] < t1) lo1 = m + 1; else hi1 = m; }
            cntG[t] = (float)(lo1 - lo0);
        }
    }
}

__global__ __launch_bounds__(256) void k_p1_gemm(const int* __restrict__ ei, const float* __restrict__ ew,
                                                 u64* pk, unsigned char* __restrict__ eslot, int e, int p1b,
                                                 const float* __restrict__ Af32,
                                                 const unsigned short* __restrict__ Wf,
                                                 const float* __restrict__ bias,
                                                 unsigned short* __restrict__ C, int M)
{
    if (blockIdx.x < p1b) {
        int i = blockIdx.x * 256 + threadIdx.x;
        if (i >= e) return;
        int c = ei[e + i];
        float w = ew[i];
        u64 fixed = (u64)((double)w * 4294967296.0);
        u64 packed = (1ULL << FRACBITS) | fixed;
        u64 old = atomicAdd(&pk[c], packed);
        eslot[i] = (unsigned char)(old >> FRACBITS);
    } else {
        gemm_dev(blockIdx.x - p1b, threadIdx.x, nullptr, Af32, Wf, bias, C, 1, M);
    }
}

__global__ __launch_bounds__(256) void k_scan1_gemm(const u64* __restrict__ pk,
                                                    int* __restrict__ start, float* __restrict__ dinv,
                                                    int* __restrict__ partials, int n, int s1b,
                                                    const unsigned short* __restrict__ A,
                                                    const unsigned short* __restrict__ Wf,
                                                    const float* __restrict__ bias,
                                                    unsigned short* __restrict__ C, int M)
{
    __shared__ int s[256];
    if (blockIdx.x < s1b) {
        int t = threadIdx.x;
        int base = blockIdx.x * 1024 + t * 4;
        int v[4];
#pragma unroll
        for (int j = 0; j < 4; ++j) {
            int idx = base + j;
            if (idx < n) {
                u64 q = pk[idx];
                v[j] = (int)(q >> FRACBITS);
                float deg = 1.0f + (float)((double)(q & FRACMASK) * (1.0 / 4294967296.0));
                dinv[idx] = 1.0f / sqrtf(deg);
            } else v[j] = 0;
        }
        int tsum = v[0] + v[1] + v[2] + v[3];
        s[t] = tsum; __syncthreads();
        for (int off = 1; off < 256; off <<= 1) {
            int xv = (t >= off) ? s[t - off] : 0;
            __syncthreads();
            s[t] += xv;
            __syncthreads();
        }
        if (t == 255) partials[blockIdx.x] = s[255];
        int run = s[t] - tsum;
#pragma unroll
        for (int j = 0; j < 4; ++j) { int idx = base + j; if (idx < n) start[idx] = run; run += v[j]; }
    } else {
        gemm_dev(blockIdx.x - s1b, threadIdx.x, A, nullptr, Wf, bias, C, 1, M);
    }
}

__global__ __launch_bounds__(256) void k_scan2_gemm(int* partials, int nb,
                                                    const unsigned short* __restrict__ A,
                                                    const unsigned short* __restrict__ Wf,
                                                    unsigned short* __restrict__ C, int M)
{
    __shared__ int s[256];
    if (blockIdx.x == 0) {
        int t = threadIdx.x;
        int offset = 0;
        for (int b0 = 0; b0 < nb; b0 += 256) {
            int v = (b0 + t < nb) ? partials[b0 + t] : 0;
            s[t] = v; __syncthreads();
            for (int off = 1; off < 256; off <<= 1) {
                int xv = (t >= off) ? s[t - off] : 0;
                __syncthreads();
                s[t] += xv;
                __syncthreads();
            }
            int excl = s[t] - v;
            int tot = s[255];
            if (b0 + t < nb) partials[b0 + t] = offset + excl;
            offset += tot;
            __syncthreads();
        }
    } else {
        gemm_dev(blockIdx.x - 1, threadIdx.x, A, nullptr, Wf, nullptr, C, 0, M);
    }
}

// scan3 (startF = start_pre + partials) || phase2 (atomic-free fill via
// start_pre + partials — no dependency on startF, so no race)
__global__ __launch_bounds__(256) void k_s3_phase2(const int* __restrict__ start_pre,
                                                   const int* __restrict__ partials,
                                                   int* __restrict__ startF, int n, int n3b, int total,
                                                   const int* __restrict__ ei, const float* __restrict__ ew,
                                                   const float* __restrict__ dinv,
                                                   const unsigned char* __restrict__ eslot,
                                                   u32* __restrict__ rec, int e)
{
    if (blockIdx.x < n3b) {
        int i = blockIdx.x * 256 + threadIdx.x;
        if (i < n) startF[i] = start_pre[i] + partials[i >> 10];
        if (i == 0) startF[n] = total;
    } else {
        int i = (blockIdx.x - n3b) * 256 + threadIdx.x;
        if (i >= e) return;
        int r = ei[i], c = ei[e + i];
        int idx = start_pre[c] + partials[c >> 10] + eslot[i];
        float w = dinv[r] * ew[i] * dinv[c];       // w >= 0
        u32 wb = f2b(w);
        rec[idx] = (wb << 17) | (u32)r;             // requires N < 2^17
    }
}

// ---- pull aggregation: 1 wave/node, 8-deep gather pipeline (R7 form) ------
__global__ __launch_bounds__(256) void k_agg(const u32* __restrict__ xw,
                                             const int* __restrict__ start,
                                             const u32* __restrict__ rec,
                                             const float* __restrict__ dinv, const float* __restrict__ bias,
                                             u32* __restrict__ hout, int n)
{
    int wid  = (blockIdx.x * 256 + threadIdx.x) >> 6;
    int lane = threadIdx.x & 63;
    if (wid >= n) return;
    float di = dinv[wid];
    float sn = di * di;
    u32 v = xw[(size_t)wid * 64 + lane];
    float ax = __uint_as_float(v << 16) * sn;
    float ay = __uint_as_float(v & 0xffff0000u) * sn;
    int s0 = start[wid], s1 = start[wid + 1];

    int j = s0;
    for (; j + 8 <= s1; j += 8) {
        u32 rc[8];
#pragma unroll
        for (int q = 0; q < 8; ++q) rc[q] = rec[j + q];
        u32 u[8];
#pragma unroll
        for (int q = 0; q < 8; ++q) u[q] = xw[(size_t)(rc[q] & 0x1FFFFu) * 64 + lane];
#pragma unroll
        for (int q = 0; q < 8; ++q) {
            float w = __uint_as_float((rc[q] >> 17) << 16);
            ax = fmaf(w, __uint_as_float(u[q] << 16), ax);
            ay = fmaf(w, __uint_as_float(u[q] & 0xffff0000u), ay);
        }
    }
    int rem = s1 - j;
    if (rem) {
        u32 rc[8];
#pragma unroll
        for (int q = 0; q < 8; ++q) rc[q] = (q < rem) ? rec[j + q] : 0u;
        u32 u[8];
#pragma unroll
        for (int q = 0; q < 8; ++q) u[q] = (q < rem) ? xw[(size_t)(rc[q] & 0x1FFFFu) * 64 + lane] : 0u;
#pragma unroll
        for (int q = 0; q < 8; ++q) {
            float w = __uint_as_float((rc[q] >> 17) << 16);
            ax = fmaf(w, __uint_as_float(u[q] << 16), ax);
            ay = fmaf(w, __uint_as_float(u[q] & 0xffff0000u), ay);
        }
    }

    ax = fmaxf(ax + bias[lane * 2], 0.f);
    ay = fmaxf(ay + bias[lane * 2 + 1], 0.f);
    hout[(size_t)wid * 64 + lane] = (u32)f2b(ax) | ((u32)f2b(ay) << 16);
}

__global__ __launch_bounds__(256) void k_pool_gemm(const unsigned short* __restrict__ h,
                                                   const int* __restrict__ batch,
                                                   float* gmax, float* gsum, int n, int pb,
                                                   const unsigned short* __restrict__ Wf,
                                                   unsigned short* __restrict__ C, int M)
{
    if (blockIdx.x < pb) {
        pool_dev(blockIdx.x, threadIdx.x, h, batch, gmax, gsum, n);
    } else {
        gemm_dev(blockIdx.x - pb, threadIdx.x, h, nullptr, Wf, nullptr, C, 0, M);
    }
}

__global__ __launch_bounds__(256) void k_pool(const unsigned short* __restrict__ h,
                                              const int* __restrict__ batch,
                                              float* gmax, float* gsum, int n)
{
    pool_dev(blockIdx.x, threadIdx.x, h, batch, gmax, gsum, n);
}

__global__ __launch_bounds__(256) void k_final(const float* __restrict__ gmax, const float* __restrict__ gsum,
                                               const float* __restrict__ cntG, float* __restrict__ out,
                                               int G, int L)
{
    int i = blockIdx.x * 256 + threadIdx.x;
    int tot = L * G * 128;
    if (i >= tot) return;
    int c = i & 127;
    int g = (i >> 7) % G;
    int l = i / (G * 128);
    float ct = fmaxf(cntG[g], 1.0f);
    out[(size_t)g * (L * 256) + l * 256 + c]       = gmax[i];
    out[(size_t)g * (L * 256) + l * 256 + 128 + c] = gsum[i] / ct;
}

static inline int divup(int a, int b) { return (a + b - 1) / b; }

extern "C" void kernel_launch(void* const* d_in, const int* in_sizes, int n_in,
                              void* d_out, int out_size, void* d_ws, size_t ws_size,
                              hipStream_t stream)
{
    const float* x     = (const float*)d_in[0];
    const float* ew    = (const float*)d_in[1];
    const float* W1    = (const float*)d_in[2];
    const float* b1    = (const float*)d_in[3];
    const float* W2    = (const float*)d_in[4];
    const float* b2    = (const float*)d_in[5];
    const float* cW    = (const float*)d_in[6];
    const float* cB    = (const float*)d_in[7];
    const int*   ei    = (const int*)d_in[8];
    const int*   batch = (const int*)d_in[9];
    float* out = (float*)d_out;

    const int E = in_sizes[1];
    const int N = in_sizes[9];
    const int L = in_sizes[7] / 128;
    const int G = out_size / (L * 256);

    char* p = (char*)d_ws;
    auto carve = [&](size_t bytes) -> void* {
        void* q = (void*)p;
        p += (bytes + 255) & ~(size_t)255;
        return q;
    };
    u64*   pk       = (u64*)  carve((size_t)N * 8);
    float* dinv     = (float*)carve((size_t)N * 4);
    int*   start    = (int*)  carve((size_t)(N + 1) * 4);   // pre-scan3 (immutable)
    int*   startF   = (int*)  carve((size_t)(N + 1) * 4);   // finalized offsets
    unsigned char* eslot = (unsigned char*)carve((size_t)E);
    int*   partials = (int*)  carve(4096);
    u32*   rec      = (u32*)  carve((size_t)E * 4);
    float* gmax     = (float*)carve((size_t)L * G * 128 * 4);
    float* gsum     = (float*)carve((size_t)L * G * 128 * 4);
    float* cntG     = (float*)carve((size_t)G * 4);
    unsigned short* wfall = (unsigned short*)carve((size_t)(2 + 3) * 16384 * 2);
    unsigned short* xwb = (unsigned short*)carve((size_t)N * 128 * 2);
    unsigned short* hbA = (unsigned short*)carve((size_t)N * 128 * 2);
    unsigned short* hbB = (unsigned short*)carve((size_t)N * 128 * 2);

    const int npool = L * G * 128;
    const int nconv = (L < 3 ? L : 3);

    // --- setup: init || wfrag x(2+nconv) || gcnt ---------------------------
    int nInit = divup(N > npool ? N : npool, 256);
    int nWf = (2 + nconv) * 8;
    k_setup<<<nInit + nWf + 1, 256, 0, stream>>>(pk, gmax, gsum, N, npool,
                                                 W1, W2, cW, wfall, nInit, nWf,
                                                 batch, cntG, G);

    int p1b = divup(E, 256);
    int gblocks = divup(N, 64);
    int pblocks = divup(N, 128);
    int ablocks = divup(N, 4);

    // --- phase1 || GEMM1 ---------------------------------------------------
    k_p1_gemm<<<p1b + gblocks, 256, 0, stream>>>(ei, ew, pk, eslot, E, p1b,
                                                 x, wfall, b1, hbA, N);

    // --- scan1 || GEMM2 ----------------------------------------------------
    int nb1 = divup(N, 1024);
    k_scan1_gemm<<<nb1 + gblocks, 256, 0, stream>>>(pk, start, dinv, partials, N, nb1,
                                                    hbA, wfall + 16384, b2, hbB, N);

    // --- scan2 || conv GEMM l0 --------------------------------------------
    k_scan2_gemm<<<1 + gblocks, 256, 0, stream>>>(partials, nb1,
                                                  hbB, wfall + 2 * 16384, xwb, N);

    // --- scan3 || phase2 ---------------------------------------------------
    int n3b = divup(N, 256);
    k_s3_phase2<<<n3b + p1b, 256, 0, stream>>>(start, partials, startF, N, n3b, E,
                                               ei, ew, dinv, eslot, rec, E);

    // --- conv layers: agg -> (pool || next conv GEMM) ----------------------
    unsigned short* cur = hbB;
    unsigned short* alt = hbA;
    for (int l = 0; l < L; ++l) {
        k_agg<<<ablocks, 256, 0, stream>>>((const u32*)xwb, startF, rec, dinv,
                                           cB + (size_t)l * 128, (u32*)alt, N);
        if (l + 1 < L) {
            int wi = 2 + (l + 1 < nconv ? l + 1 : nconv - 1);
            k_pool_gemm<<<pblocks + gblocks, 256, 0, stream>>>(alt, batch,
                                                               gmax + (size_t)l * G * 128,
                                                               gsum + (size_t)l * G * 128, N, pblocks,
                                                               wfall + (size_t)wi * 16384, xwb, N);
        } else {
            k_pool<<<pblocks, 256, 0, stream>>>(alt, batch,
                                                gmax + (size_t)l * G * 128,
                                                gsum + (size_t)l * G * 128, N);
        }
        unsigned short* tmp = cur; cur = alt; alt = tmp;
    }

    k_final<<<divup(L * G * 128, 256), 256, 0, stream>>>(gmax, gsum, cntG, out, G, L);
}

// Round 12
// 478.360 us; speedup vs baseline: 1.0209x; 1.0042x over previous
//
#include <hip/hip_runtime.h>

// ---------------------------------------------------------------------------
// CustomGCN: 2 dense layers + 3 GCNConv layers + per-layer (max||mean) pool.
// R1: binary-search cntG.  R2: bf16 pipeline + MFMA GEMMs + bf16 gather.
// R3: 8-deep agg gather pipeline.  R4: one u64 atomic/edge CSC build.
// R5: interleaved CSC record.  R6: 4B rec ((bf16w)<<17|src), u8 eslot.
// R7: agg 8-deep 1-wave.  R8: block-range fusion.  R9: 2-wave agg regressed.
// R10: scan3+phase2 fused.
// R11: GEMM blocks FIRST in fused kernels (appended-last blocks never
//      overlapped — scheduler drained phase1 before any GEMM got a slot);
//      scan2 deleted: consumers redundantly prefix-scan the 98 block sums
//      in LDS; conv-gemm-l0 + scan3 + phase2 merged into one kernel.
// ---------------------------------------------------------------------------

typedef __attribute__((ext_vector_type(8))) short bf16x8;
typedef __attribute__((ext_vector_type(4))) float f32x4;
typedef unsigned long long u64;
typedef unsigned int u32;

#define FRACBITS 52
#define FRACMASK ((1ULL << FRACBITS) - 1ULL)

__device__ __forceinline__ unsigned short f2b(float f) {  // RNE f32->bf16
    unsigned int u = __float_as_uint(f);
    return (unsigned short)((u + 0x7fffu + ((u >> 16) & 1u)) >> 16);
}
__device__ __forceinline__ float b2f(unsigned short h) {
    return __uint_as_float((unsigned int)h << 16);
}

// ---------------- device bodies --------------------------------------------

__device__ __forceinline__ void gemm_dev(int bidx, int t,
                                         const unsigned short* __restrict__ A,
                                         const float* __restrict__ Af32,
                                         const unsigned short* __restrict__ Wf,
                                         const float* __restrict__ bias,
                                         unsigned short* __restrict__ C,
                                         int relu, int M)
{
    int lane = t & 63, w = t >> 6;
    int s = bidx * 4 + w;
    if (s * 16 >= M) return;
    int r0 = s * 16;
    int row = r0 + (lane & 15);
    int k0 = (lane >> 4) * 8;

    bf16x8 af[4];
    if (A) {
#pragma unroll
        for (int kt = 0; kt < 4; ++kt) {
            bf16x8 a = {0,0,0,0,0,0,0,0};
            if (row < M) a = *(const bf16x8*)&A[(size_t)row * 128 + k0 + kt * 32];
            af[kt] = a;
        }
    } else {
#pragma unroll
        for (int kt = 0; kt < 4; ++kt) {
            bf16x8 a = {0,0,0,0,0,0,0,0};
            if (row < M) {
                const float4* A4 = (const float4*)(Af32 + (size_t)row * 128 + k0 + kt * 32);
                float4 p = A4[0], q = A4[1];
                a[0] = (short)f2b(p.x); a[1] = (short)f2b(p.y);
                a[2] = (short)f2b(p.z); a[3] = (short)f2b(p.w);
                a[4] = (short)f2b(q.x); a[5] = (short)f2b(q.y);
                a[6] = (short)f2b(q.z); a[7] = (short)f2b(q.w);
            }
            af[kt] = a;
        }
    }

    int orow = r0 + 4 * (lane >> 4);
    int ocol = lane & 15;
#pragma unroll
    for (int ct = 0; ct < 8; ++ct) {
        f32x4 acc = {0.f, 0.f, 0.f, 0.f};
#pragma unroll
        for (int kt = 0; kt < 4; ++kt) {
            bf16x8 b = *(const bf16x8*)&Wf[(size_t)(((ct << 2) | kt) * 64 + lane) * 8];
            acc = __builtin_amdgcn_mfma_f32_16x16x32_bf16(af[kt], b, acc, 0, 0, 0);
        }
        float bv = bias ? bias[ct * 16 + ocol] : 0.f;
#pragma unroll
        for (int j = 0; j < 4; ++j) {
            int rr = orow + j;
            if (rr < M) {
                float v = acc[j] + bv;
                if (relu) v = fmaxf(v, 0.f);
                C[(size_t)rr * 128 + ct * 16 + ocol] = f2b(v);
            }
        }
    }
}

__device__ __forceinline__ void pool_dev(int bidx, int t,
                                         const unsigned short* __restrict__ h,
                                         const int* __restrict__ batch,
                                         float* gmax, float* gsum, int n)
{
    int c = t & 127, sub = t >> 7;
    int r0 = bidx * 128;
    int rend = min(r0 + 128, n);
    float mx = 0.f, sm = 0.f;
    int cur = -1;
    for (int r = r0 + sub; r < rend; r += 2) {
        int b = batch[r];
        if (b != cur) {
            if (cur >= 0) {
                atomicMax((unsigned int*)&gmax[cur * 128 + c], __float_as_uint(mx));
                atomicAdd(&gsum[cur * 128 + c], sm);
            }
            cur = b; mx = 0.f; sm = 0.f;
        }
        float v = b2f(h[(size_t)r * 128 + c]);
        mx = fmaxf(mx, v);
        sm += v;
    }
    if (cur >= 0) {
        atomicMax((unsigned int*)&gmax[cur * 128 + c], __float_as_uint(mx));
        atomicAdd(&gsum[cur * 128 + c], sm);
    }
}

// ---------------- fused kernels --------------------------------------------

__global__ __launch_bounds__(256) void k_setup(u64* __restrict__ pk,
                                               float* __restrict__ gmax, float* __restrict__ gsum,
                                               int n, int npool,
                                               const float* __restrict__ W1, const float* __restrict__ W2,
                                               const float* __restrict__ cW,
                                               unsigned short* __restrict__ wfall,
                                               int nInit, int nWf,
                                               const int* __restrict__ batch, float* __restrict__ cntG, int g)
{
    int b = blockIdx.x;
    if (b < nInit) {
        int i = b * 256 + threadIdx.x;
        if (i < n) pk[i] = 0ULL;
        if (i < npool) { gmax[i] = 0.0f; gsum[i] = 0.0f; }
    } else if (b < nInit + nWf) {
        int wb = b - nInit;
        int m = wb >> 3;
        const float* W = (m == 0) ? W1 : (m == 1) ? W2 : (cW + (size_t)(m - 2) * 16384);
        unsigned short* Wf = wfall + (size_t)m * 16384;
        int idx = (wb & 7) * 256 + threadIdx.x;   // [0, 2048)
        int ctkt = idx >> 6, lane = idx & 63;
        int kt = ctkt & 3, ct = ctkt >> 2;
        int k0 = kt * 32 + (lane >> 4) * 8;
        int col = ct * 16 + (lane & 15);
        bf16x8 v;
#pragma unroll
        for (int j = 0; j < 8; ++j) v[j] = (short)f2b(W[(k0 + j) * 128 + col]);
        *(bf16x8*)&Wf[(size_t)idx * 8] = v;
    } else {
        int t = threadIdx.x;
        if (t < g) {
            int lo0 = 0, hi0 = n;
            while (lo0 < hi0) { int m = (lo0 + hi0) >> 1; if (batch[m] < t) lo0 = m + 1; else hi0 = m; }
            int lo1 = lo0, hi1 = n, t1 = t + 1;
            while (lo1 < hi1) { int m = (lo1 + hi1) >> 1; if (batch[m] < t1) lo1 = m + 1; else hi1 = m; }
            cntG[t] = (float)(lo1 - lo0);
        }
    }
}

// GEMM1 blocks FIRST, then phase1 (atomic CSC count/degree/slot).
__global__ __launch_bounds__(256) void k_p1_gemm(const int* __restrict__ ei, const float* __restrict__ ew,
                                                 u64* pk, unsigned char* __restrict__ eslot, int e, int gb,
                                                 const float* __restrict__ Af32,
                                                 const unsigned short* __restrict__ Wf,
                                                 const float* __restrict__ bias,
                                                 unsigned short* __restrict__ C, int M)
{
    if (blockIdx.x < gb) {
        gemm_dev(blockIdx.x, threadIdx.x, nullptr, Af32, Wf, bias, C, 1, M);
    } else {
        int i = (blockIdx.x - gb) * 256 + threadIdx.x;
        if (i >= e) return;
        int c = ei[e + i];
        float w = ew[i];
        u64 fixed = (u64)((double)w * 4294967296.0);
        u64 packed = (1ULL << FRACBITS) | fixed;
        u64 old = atomicAdd(&pk[c], packed);
        eslot[i] = (unsigned char)(old >> FRACBITS);
    }
}

// scan1 blocks first (few), then GEMM2. psum keeps RAW block sums.
__global__ __launch_bounds__(256) void k_scan1_gemm(const u64* __restrict__ pk,
                                                    int* __restrict__ start, float* __restrict__ dinv,
                                                    int* __restrict__ psum, int n, int s1b,
                                                    const unsigned short* __restrict__ A,
                                                    const unsigned short* __restrict__ Wf,
                                                    const float* __restrict__ bias,
                                                    unsigned short* __restrict__ C, int M)
{
    __shared__ int s[256];
    if (blockIdx.x < s1b) {
        int t = threadIdx.x;
        int base = blockIdx.x * 1024 + t * 4;
        int v[4];
#pragma unroll
        for (int j = 0; j < 4; ++j) {
            int idx = base + j;
            if (idx < n) {
                u64 q = pk[idx];
                v[j] = (int)(q >> FRACBITS);
                float deg = 1.0f + (float)((double)(q & FRACMASK) * (1.0 / 4294967296.0));
                dinv[idx] = 1.0f / sqrtf(deg);
            } else v[j] = 0;
        }
        int tsum = v[0] + v[1] + v[2] + v[3];
        s[t] = tsum; __syncthreads();
        for (int off = 1; off < 256; off <<= 1) {
            int xv = (t >= off) ? s[t - off] : 0;
            __syncthreads();
            s[t] += xv;
            __syncthreads();
        }
        if (t == 255) psum[blockIdx.x] = s[255];
        int run = s[t] - tsum;
#pragma unroll
        for (int j = 0; j < 4; ++j) { int idx = base + j; if (idx < n) start[idx] = run; run += v[j]; }
    } else {
        gemm_dev(blockIdx.x - s1b, threadIdx.x, A, nullptr, Wf, bias, C, 1, M);
    }
}

// conv GEMM l0 (first) || scan3 (startF) || phase2 (rec fill).
// scan3/phase2 blocks redundantly prefix-scan psum[0..nb) in LDS (nb <= 1024).
__global__ __launch_bounds__(256) void k_fill_gemm(const int* __restrict__ start_pre,
                                                   const int* __restrict__ psum, int nb,
                                                   int* __restrict__ startF, int n, int n3b, int gb,
                                                   const int* __restrict__ ei, const float* __restrict__ ew,
                                                   const float* __restrict__ dinv,
                                                   const unsigned char* __restrict__ eslot,
                                                   u32* __restrict__ rec, int e,
                                                   const unsigned short* __restrict__ A,
                                                   const unsigned short* __restrict__ Wf,
                                                   unsigned short* __restrict__ C, int M)
{
    if (blockIdx.x < gb) {
        gemm_dev(blockIdx.x, threadIdx.x, A, nullptr, Wf, nullptr, C, 0, M);
        return;
    }
    __shared__ int s[256];
    __shared__ int pref[1024];
    int t = threadIdx.x;
    {   // exclusive prefix of psum into pref
        int offset = 0;
        for (int b0 = 0; b0 < nb; b0 += 256) {
            int v = (b0 + t < nb) ? psum[b0 + t] : 0;
            s[t] = v; __syncthreads();
            for (int off = 1; off < 256; off <<= 1) {
                int xv = (t >= off) ? s[t - off] : 0;
                __syncthreads();
                s[t] += xv;
                __syncthreads();
            }
            if (b0 + t < nb) pref[b0 + t] = offset + s[t] - v;
            offset += s[255];
            __syncthreads();
        }
    }
    int b = blockIdx.x - gb;
    if (b < n3b) {
        int i = b * 256 + t;
        if (i < n) startF[i] = start_pre[i] + pref[i >> 10];
        if (i == 0) startF[n] = e;
    } else {
        int i = (b - n3b) * 256 + t;
        if (i >= e) return;
        int r = ei[i], c = ei[e + i];
        int idx = start_pre[c] + pref[c >> 10] + eslot[i];
        float w = dinv[r] * ew[i] * dinv[c];       // w >= 0
        u32 wb = f2b(w);
        rec[idx] = (wb << 17) | (u32)r;             // requires N < 2^17
    }
}

// ---- pull aggregation: 1 wave/node, 8-deep gather pipeline ----------------
__global__ __launch_bounds__(256) void k_agg(const u32* __restrict__ xw,
                                             const int* __restrict__ start,
                                             const u32* __restrict__ rec,
                                             const float* __restrict__ dinv, const float* __restrict__ bias,
                                             u32* __restrict__ hout, int n)
{
    int wid  = (blockIdx.x * 256 + threadIdx.x) >> 6;
    int lane = threadIdx.x & 63;
    if (wid >= n) return;
    float di = dinv[wid];
    float sn = di * di;
    u32 v = xw[(size_t)wid * 64 + lane];
    float ax = __uint_as_float(v << 16) * sn;
    float ay = __uint_as_float(v & 0xffff0000u) * sn;
    int s0 = start[wid], s1 = start[wid + 1];

    int j = s0;
    for (; j + 8 <= s1; j += 8) {
        u32 rc[8];
#pragma unroll
        for (int q = 0; q < 8; ++q) rc[q] = rec[j + q];
        u32 u[8];
#pragma unroll
        for (int q = 0; q < 8; ++q) u[q] = xw[(size_t)(rc[q] & 0x1FFFFu) * 64 + lane];
#pragma unroll
        for (int q = 0; q < 8; ++q) {
            float w = __uint_as_float((rc[q] >> 17) << 16);
            ax = fmaf(w, __uint_as_float(u[q] << 16), ax);
            ay = fmaf(w, __uint_as_float(u[q] & 0xffff0000u), ay);
        }
    }
    int rem = s1 - j;
    if (rem) {
        u32 rc[8];
#pragma unroll
        for (int q = 0; q < 8; ++q) rc[q] = (q < rem) ? rec[j + q] : 0u;
        u32 u[8];
#pragma unroll
        for (int q = 0; q < 8; ++q) u[q] = (q < rem) ? xw[(size_t)(rc[q] & 0x1FFFFu) * 64 + lane] : 0u;
#pragma unroll
        for (int q = 0; q < 8; ++q) {
            float w = __uint_as_float((rc[q] >> 17) << 16);
            ax = fmaf(w, __uint_as_float(u[q] << 16), ax);
            ay = fmaf(w, __uint_as_float(u[q] & 0xffff0000u), ay);
        }
    }

    ax = fmaxf(ax + bias[lane * 2], 0.f);
    ay = fmaxf(ay + bias[lane * 2 + 1], 0.f);
    hout[(size_t)wid * 64 + lane] = (u32)f2b(ax) | ((u32)f2b(ay) << 16);
}

// conv GEMM(l+1) blocks first, then pool(l) — both read the same agg output h
__global__ __launch_bounds__(256) void k_pool_gemm(const unsigned short* __restrict__ h,
                                                   const int* __restrict__ batch,
                                                   float* gmax, float* gsum, int n, int gb,
                                                   const unsigned short* __restrict__ Wf,
                                                   unsigned short* __restrict__ C, int M)
{
    if (blockIdx.x < gb) {
        gemm_dev(blockIdx.x, threadIdx.x, h, nullptr, Wf, nullptr, C, 0, M);
    } else {
        pool_dev(blockIdx.x - gb, threadIdx.x, h, batch, gmax, gsum, n);
    }
}

__global__ __launch_bounds__(256) void k_pool(const unsigned short* __restrict__ h,
                                              const int* __restrict__ batch,
                                              float* gmax, float* gsum, int n)
{
    pool_dev(blockIdx.x, threadIdx.x, h, batch, gmax, gsum, n);
}

__global__ __launch_bounds__(256) void k_final(const float* __restrict__ gmax, const float* __restrict__ gsum,
                                               const float* __restrict__ cntG, float* __restrict__ out,
                                               int G, int L)
{
    int i = blockIdx.x * 256 + threadIdx.x;
    int tot = L * G * 128;
    if (i >= tot) return;
    int c = i & 127;
    int g = (i >> 7) % G;
    int l = i / (G * 128);
    float ct = fmaxf(cntG[g], 1.0f);
    out[(size_t)g * (L * 256) + l * 256 + c]       = gmax[i];
    out[(size_t)g * (L * 256) + l * 256 + 128 + c] = gsum[i] / ct;
}

static inline int divup(int a, int b) { return (a + b - 1) / b; }

extern "C" void kernel_launch(void* const* d_in, const int* in_sizes, int n_in,
                              void* d_out, int out_size, void* d_ws, size_t ws_size,
                              hipStream_t stream)
{
    const float* x     = (const float*)d_in[0];
    const float* ew    = (const float*)d_in[1];
    const float* W1    = (const float*)d_in[2];
    const float* b1    = (const float*)d_in[3];
    const float* W2    = (const float*)d_in[4];
    const float* b2    = (const float*)d_in[5];
    const float* cW    = (const float*)d_in[6];
    const float* cB    = (const float*)d_in[7];
    const int*   ei    = (const int*)d_in[8];
    const int*   batch = (const int*)d_in[9];
    float* out = (float*)d_out;

    const int E = in_sizes[1];
    const int N = in_sizes[9];
    const int L = in_sizes[7] / 128;
    const int G = out_size / (L * 256);

    char* p = (char*)d_ws;
    auto carve = [&](size_t bytes) -> void* {
        void* q = (void*)p;
        p += (bytes + 255) & ~(size_t)255;
        return q;
    };
    u64*   pk       = (u64*)  carve((size_t)N * 8);
    float* dinv     = (float*)carve((size_t)N * 4);
    int*   start    = (int*)  carve((size_t)(N + 1) * 4);   // pre-scan3 (immutable)
    int*   startF   = (int*)  carve((size_t)(N + 1) * 4);   // finalized offsets
    unsigned char* eslot = (unsigned char*)carve((size_t)E);
    int*   psum     = (int*)  carve(4096);                  // raw block sums
    u32*   rec      = (u32*)  carve((size_t)E * 4);
    float* gmax     = (float*)carve((size_t)L * G * 128 * 4);
    float* gsum     = (float*)carve((size_t)L * G * 128 * 4);
    float* cntG     = (float*)carve((size_t)G * 4);
    unsigned short* wfall = (unsigned short*)carve((size_t)(2 + 3) * 16384 * 2);
    unsigned short* xwb = (unsigned short*)carve((size_t)N * 128 * 2);
    unsigned short* hbA = (unsigned short*)carve((size_t)N * 128 * 2);
    unsigned short* hbB = (unsigned short*)carve((size_t)N * 128 * 2);

    const int npool = L * G * 128;
    const int nconv = (L < 3 ? L : 3);

    // --- setup: init || wfrag x(2+nconv) || gcnt ---------------------------
    int nInit = divup(N > npool ? N : npool, 256);
    int nWf = (2 + nconv) * 8;
    k_setup<<<nInit + nWf + 1, 256, 0, stream>>>(pk, gmax, gsum, N, npool,
                                                 W1, W2, cW, wfall, nInit, nWf,
                                                 batch, cntG, G);

    int p1b = divup(E, 256);
    int gblocks = divup(N, 64);
    int pblocks = divup(N, 128);
    int ablocks = divup(N, 4);

    // --- GEMM1 (first) || phase1 ------------------------------------------
    k_p1_gemm<<<gblocks + p1b, 256, 0, stream>>>(ei, ew, pk, eslot, E, gblocks,
                                                 x, wfall, b1, hbA, N);

    // --- scan1 || GEMM2 ----------------------------------------------------
    int nb1 = divup(N, 1024);
    k_scan1_gemm<<<nb1 + gblocks, 256, 0, stream>>>(pk, start, dinv, psum, N, nb1,
                                                    hbA, wfall + 16384, b2, hbB, N);

    // --- conv GEMM l0 (first) || scan3 || phase2 ---------------------------
    int n3b = divup(N, 256);
    k_fill_gemm<<<gblocks + n3b + p1b, 256, 0, stream>>>(start, psum, nb1,
                                                         startF, N, n3b, gblocks,
                                                         ei, ew, dinv, eslot, rec, E,
                                                         hbB, wfall + 2 * 16384, xwb, N);

    // --- conv layers: agg -> (next conv GEMM || pool) ----------------------
    unsigned short* cur = hbB;
    unsigned short* alt = hbA;
    for (int l = 0; l < L; ++l) {
        k_agg<<<ablocks, 256, 0, stream>>>((const u32*)xwb, startF, rec, dinv,
                                           cB + (size_t)l * 128, (u32*)alt, N);
        if (l + 1 < L) {
            int wi = 2 + (l + 1 < nconv ? l + 1 : nconv - 1);
            k_pool_gemm<<<gblocks + pblocks, 256, 0, stream>>>(alt, batch,
                                                               gmax + (size_t)l * G * 128,
                                                               gsum + (size_t)l * G * 128, N, gblocks,
                                                               wfall + (size_t)wi * 16384, xwb, N);
        } else {
            k_pool<<<pblocks, 256, 0, stream>>>(alt, batch,
                                                gmax + (size_t)l * G * 128,
                                                gsum + (size_t)l * G * 128, N);
        }
        unsigned short* tmp = cur; cur = alt; alt = tmp;
    }

    k_final<<<divup(L * G * 128, 256), 256, 0, stream>>>(gmax, gsum, cntG, out, G, L);
}